// Round 1
// baseline (264.055 us; speedup 1.0000x reference)
//
#include <hip/hip_runtime.h>
#include <hip/hip_bf16.h>
#include <math.h>

#define NB 16
#define NS 2048
#define NH 128

typedef __attribute__((ext_vector_type(8))) short bf16x8;
typedef __attribute__((ext_vector_type(4))) float f32x4;
typedef __attribute__((ext_vector_type(4))) unsigned short u16x4;

__device__ __forceinline__ ushort f2bf(float f) {
  unsigned u = __float_as_uint(f);
  u += 0x7fffu + ((u >> 16) & 1u);
  return (ushort)(u >> 16);
}
__device__ __forceinline__ float bf2f(ushort h) {
  return __uint_as_float(((unsigned)h) << 16);
}

// out[b,x,h] = sum_y softmax_y( sum_h' k[b,x,h'] q[b,y,h'] ) * v[b,y,h]
// i.e. flash attention with A-rows = k-rows, streamed over y (q/v rows).
__global__ __launch_bounds__(256, 2)
void attn_kernel(const float* __restrict__ qp, const float* __restrict__ kp,
                 const float* __restrict__ vp, float* __restrict__ op) {
  // Q tile 64x128 split hi/lo, XOR-swizzled: idx = y*128 + (h ^ ((y&7)<<3))
  __shared__ ushort q_hi[64 * 128];
  __shared__ ushort q_lo[64 * 128];
  // V tile transposed [h][y], padded stride 72 (conflict-free b128 reads)
  __shared__ ushort v_t[128 * 72];
  // per-wave P tile [16][64], XOR-swizzled
  __shared__ ushort p_lds[4 * 16 * 64];

  const int tid  = threadIdx.x;
  const int wave = tid >> 6;
  const int lane = tid & 63;
  const int g    = lane >> 4;   // 16-lane group 0..3
  const int li   = lane & 15;

  const int b     = blockIdx.x >> 5;        // 512 blocks = 16 b * 32 xtiles
  const int xbase = (blockIdx.x & 31) * 64;
  const int xw    = xbase + wave * 16;      // this wave's 16 x-rows

  // ---- hoisted K fragments (A operand), split bf16 hi/lo ----
  // A-frag (16x16x32): lane holds A[row=li][k = kk*32 + 8*g + e], e=0..7
  bf16x8 khi[4], klo[4];
  {
    const float* kr = kp + ((size_t)(b * NS + xw + li)) * NH + g * 8;
    #pragma unroll
    for (int kk = 0; kk < 4; ++kk) {
      f32x4 a0 = *(const f32x4*)(kr + kk * 32);
      f32x4 a1 = *(const f32x4*)(kr + kk * 32 + 4);
      #pragma unroll
      for (int e = 0; e < 8; ++e) {
        float x = (e < 4) ? a0[e] : a1[e - 4];
        ushort h = f2bf(x);
        khi[kk][e] = (short)h;
        klo[kk][e] = (short)f2bf(x - bf2f(h));
      }
    }
  }

  float m_[4], l_[4];
  f32x4 o_[8];
  #pragma unroll
  for (int r = 0; r < 4; ++r) { m_[r] = -INFINITY; l_[r] = 0.f; }
  #pragma unroll
  for (int h = 0; h < 8; ++h) o_[h] = (f32x4){0.f, 0.f, 0.f, 0.f};

  const float* qb = qp + (size_t)b * NS * NH;
  const float* vb = vp + (size_t)b * NS * NH;

  for (int yt = 0; yt < NS / 64; ++yt) {
    const int yb = yt * 64;

    // ---- stage Q tile (hi/lo bf16, swizzled), coalesced f32x4 loads ----
    #pragma unroll
    for (int f = 0; f < 8; ++f) {
      int j  = tid + 256 * f;       // float4 index within 64x128 tile
      int rr = j >> 5;              // y row 0..63
      int cc = (j & 31) << 2;       // h col, step 4
      f32x4 qv = *(const f32x4*)(qb + (size_t)(yb + rr) * NH + cc);
      u16x4 hv, lv;
      #pragma unroll
      for (int i = 0; i < 4; ++i) {
        float x = qv[i];
        ushort h = f2bf(x);
        hv[i] = h;
        lv[i] = f2bf(x - bf2f(h));
      }
      int idx = rr * 128 + (cc ^ ((rr & 7) << 3));
      *(u16x4*)&q_hi[idx] = hv;
      *(u16x4*)&q_lo[idx] = lv;
    }

    // ---- stage V transposed: v_t[h][y] (bf16), pair rows via shfl ----
    #pragma unroll
    for (int f = 0; f < 8; ++f) {
      int j  = tid + 256 * f;
      int rr = j >> 5;              // y row 0..63
      int cc = (j & 31) << 2;       // h col
      f32x4 vv = *(const f32x4*)(vb + (size_t)(yb + rr) * NH + cc);
      ushort mh[4];
      #pragma unroll
      for (int i = 0; i < 4; ++i) mh[i] = f2bf(vv[i]);
      unsigned mx = (unsigned)mh[0] | ((unsigned)mh[1] << 16);
      unsigned my = (unsigned)mh[2] | ((unsigned)mh[3] << 16);
      unsigned ox = (unsigned)__shfl_xor((int)mx, 32);  // partner row rr^1
      unsigned oy = (unsigned)__shfl_xor((int)my, 32);
      ushort oh[4] = {(ushort)(ox & 0xffffu), (ushort)(ox >> 16),
                      (ushort)(oy & 0xffffu), (ushort)(oy >> 16)};
      int y2 = rr & ~1;
      int bi = (rr & 1) ? 2 : 0;    // even row writes cols i=0,1; odd i=2,3
      #pragma unroll
      for (int i2 = 0; i2 < 2; ++i2) {
        int i = bi + i2;
        unsigned w = (rr & 1) ? ((unsigned)oh[i] | ((unsigned)mh[i] << 16))
                              : ((unsigned)mh[i] | ((unsigned)oh[i] << 16));
        *(unsigned*)&v_t[(cc + i) * 72 + y2] = w;
      }
    }
    __syncthreads();

    // ---- QK^T, split bf16 3-pass: khi*qhi + klo*qhi + khi*qlo ----
    f32x4 sa[4];
    #pragma unroll
    for (int c = 0; c < 4; ++c) sa[c] = (f32x4){0.f, 0.f, 0.f, 0.f};
    #pragma unroll
    for (int c = 0; c < 4; ++c) {
      int y = 16 * c + li;          // B-frag: col=li -> this y row of Q
      int rowoff = y * 128;
      int sw = (y & 7) << 3;
      #pragma unroll
      for (int kk = 0; kk < 4; ++kk) {
        int co = (kk * 32 + 8 * g) ^ sw;
        bf16x8 qh = *(const bf16x8*)&q_hi[rowoff + co];
        bf16x8 ql = *(const bf16x8*)&q_lo[rowoff + co];
        sa[c] = __builtin_amdgcn_mfma_f32_16x16x32_bf16(khi[kk], qh, sa[c], 0, 0, 0);
        sa[c] = __builtin_amdgcn_mfma_f32_16x16x32_bf16(klo[kk], qh, sa[c], 0, 0, 0);
        sa[c] = __builtin_amdgcn_mfma_f32_16x16x32_bf16(khi[kk], ql, sa[c], 0, 0, 0);
      }
    }

    // ---- online softmax over y (cols): reduce regs + 16-lane shfl ----
    // D layout: value sa[c][r] = S[x = 4g+r][y = 16c+li]
    float rm[4];
    #pragma unroll
    for (int r = 0; r < 4; ++r)
      rm[r] = fmaxf(fmaxf(sa[0][r], sa[1][r]), fmaxf(sa[2][r], sa[3][r]));
    #pragma unroll
    for (int msk = 1; msk <= 8; msk <<= 1) {
      #pragma unroll
      for (int r = 0; r < 4; ++r)
        rm[r] = fmaxf(rm[r], __shfl_xor(rm[r], msk));
    }
    float mn[4], corr[4];
    #pragma unroll
    for (int r = 0; r < 4; ++r) {
      mn[r]  = fmaxf(m_[r], rm[r]);
      corr[r] = __expf(m_[r] - mn[r]);
      m_[r]  = mn[r];
    }
    float p[4][4];
    float rs[4] = {0.f, 0.f, 0.f, 0.f};
    #pragma unroll
    for (int c = 0; c < 4; ++c) {
      #pragma unroll
      for (int r = 0; r < 4; ++r) {
        float e = __expf(sa[c][r] - mn[r]);
        p[c][r] = e;
        rs[r] += e;
      }
    }
    #pragma unroll
    for (int msk = 1; msk <= 8; msk <<= 1) {
      #pragma unroll
      for (int r = 0; r < 4; ++r)
        rs[r] += __shfl_xor(rs[r], msk);
    }
    #pragma unroll
    for (int r = 0; r < 4; ++r) l_[r] = l_[r] * corr[r] + rs[r];
    #pragma unroll
    for (int h = 0; h < 8; ++h) {
      #pragma unroll
      for (int r = 0; r < 4; ++r) o_[h][r] *= corr[r];
    }

    // ---- P -> per-wave LDS (bf16, swizzled) ----
    ushort* pw = p_lds + wave * 1024;
    #pragma unroll
    for (int c = 0; c < 4; ++c) {
      #pragma unroll
      for (int r = 0; r < 4; ++r) {
        int row = 4 * g + r;
        pw[row * 64 + ((16 * c + li) ^ ((row & 7) << 3))] = f2bf(p[c][r]);
      }
    }

    // ---- PV: O[16][128] += P[16][64] * V[64][128] ----
    #pragma unroll
    for (int k2 = 0; k2 < 2; ++k2) {
      bf16x8 pa = *(const bf16x8*)&pw[li * 64 + ((k2 * 32 + 8 * g) ^ ((li & 7) << 3))];
      #pragma unroll
      for (int hs = 0; hs < 8; ++hs) {
        bf16x8 vfr = *(const bf16x8*)&v_t[(hs * 16 + li) * 72 + k2 * 32 + 8 * g];
        o_[hs] = __builtin_amdgcn_mfma_f32_16x16x32_bf16(pa, vfr, o_[hs], 0, 0, 0);
      }
    }
    __syncthreads();
  }

  // ---- epilogue: normalize, store fp32 ----
  float inv[4];
  #pragma unroll
  for (int r = 0; r < 4; ++r) inv[r] = 1.0f / l_[r];
  float* ob = op + ((size_t)(b * NS + xw)) * NH;
  #pragma unroll
  for (int hs = 0; hs < 8; ++hs) {
    #pragma unroll
    for (int r = 0; r < 4; ++r)
      ob[(size_t)(4 * g + r) * NH + hs * 16 + li] = o_[hs][r] * inv[r];
  }
}

extern "C" void kernel_launch(void* const* d_in, const int* in_sizes, int n_in,
                              void* d_out, int out_size, void* d_ws, size_t ws_size,
                              hipStream_t stream) {
  const float* q = (const float*)d_in[0];
  const float* k = (const float*)d_in[1];
  const float* v = (const float*)d_in[2];
  float* out = (float*)d_out;
  dim3 grid(NB * (NS / 64));   // 512 workgroups
  dim3 block(256);
  hipLaunchKernelGGL(attn_kernel, grid, block, 0, stream, q, k, v, out);
}

// Round 2
// 100.728 us; speedup vs baseline: 2.6215x; 2.6215x over previous
//
#include <hip/hip_runtime.h>
#include <hip/hip_bf16.h>
#include <hip/hip_fp16.h>
#include <math.h>

#define NB 16
#define NS 2048
#define NH 128
#define YT_N (NS / 64)

typedef _Float16 f16;
typedef __attribute__((ext_vector_type(8))) _Float16 f16x8;
typedef __attribute__((ext_vector_type(4))) float f32x4;
typedef __attribute__((ext_vector_type(4))) unsigned short u16x4;
typedef __attribute__((ext_vector_type(8))) unsigned short u16x8;

__device__ __forceinline__ ushort f2h(float x) {
  f16 h = (f16)x;                      // v_cvt_f16_f32 (RNE)
  return __builtin_bit_cast(ushort, h);
}

__device__ __forceinline__ void gload_lds16(const void* g, void* l) {
  __builtin_amdgcn_global_load_lds(
      (const __attribute__((address_space(1))) void*)g,
      (__attribute__((address_space(3))) void*)l, 16, 0, 0);
}

// ---------- pre-pass: Q fp32 -> fp16 tiles, XOR-swizzled ----------
// qws tile (b*32+yt): off = yl*128 + (h ^ 8*(yl&7)), 8192 ushorts / tile
__global__ __launch_bounds__(256)
void conv_q_kernel(const float* __restrict__ qp, ushort* __restrict__ qws) {
  int t = blockIdx.x * 256 + threadIdx.x;      // 524288 threads
  int chunk = t & 15;
  int row = t >> 4;                            // b*2048 + y
  int h = chunk << 3;
  const float* src = qp + (size_t)row * NH + h;
  f32x4 a0 = *(const f32x4*)src;
  f32x4 a1 = *(const f32x4*)(src + 4);
  u16x8 o;
  #pragma unroll
  for (int i = 0; i < 4; ++i) { o[i] = f2h(a0[i]); o[4 + i] = f2h(a1[i]); }
  int yl = row & 63;
  size_t off = ((size_t)(row >> 6)) * 8192 + yl * 128 + (h ^ ((yl & 7) << 3));
  *(u16x8*)(qws + off) = o;
}

// ---------- pre-pass: V fp32 -> fp16 transposed tiles, swizzled ----------
// vtws tile (b*32+yt): element V[y][h] at off = h*64 + (y ^ 8*(h&7))
__global__ __launch_bounds__(256)
void conv_vt_kernel(const float* __restrict__ vp, ushort* __restrict__ vtws) {
  __shared__ ushort tile[64 * 132];
  int t = threadIdx.x;
  int bt = blockIdx.x;                          // b*32 + yt
  const float* src = vp + (size_t)bt * (64 * NH);
  #pragma unroll
  for (int rep = 0; rep < 4; ++rep) {
    int c8 = t + 256 * rep;                     // 0..1023
    int r = c8 >> 4, h = (c8 & 15) << 3;
    f32x4 a0 = *(const f32x4*)(src + (size_t)r * NH + h);
    f32x4 a1 = *(const f32x4*)(src + (size_t)r * NH + h + 4);
    u16x8 o;
    #pragma unroll
    for (int i = 0; i < 4; ++i) { o[i] = f2h(a0[i]); o[4 + i] = f2h(a1[i]); }
    *(u16x8*)&tile[r * 132 + h] = o;
  }
  __syncthreads();
  ushort* dst = vtws + (size_t)bt * 8192;
  #pragma unroll
  for (int rep = 0; rep < 4; ++rep) {
    int wid = t + 256 * rep;                    // 0..1023
    int hp = wid >> 3, y8 = (wid & 7) << 3;
    u16x8 o;
    #pragma unroll
    for (int i = 0; i < 8; ++i) o[i] = tile[(y8 + i) * 132 + hp];
    *(u16x8*)&dst[hp * 64 + (y8 ^ ((hp & 7) << 3))] = o;
  }
}

// ---------- main attention ----------
// out[b,x,h] = sum_y softmax_y(K[b,x,:]·Q[b,y,:]) * V[b,y,h]
template <bool PRECONV>
__global__ __launch_bounds__(256, 2)
void attn_main(const float* __restrict__ qp, const float* __restrict__ kp,
               const float* __restrict__ vp, float* __restrict__ op,
               const ushort* __restrict__ qws, const ushort* __restrict__ vtws) {
  __shared__ ushort qb[2][64 * 128];   // Q tile, swizzled: y*128 + (h ^ 8*(y&7))
  __shared__ ushort vb[2][128 * 64];   // V^T tile, swizzled: h*64 + (y ^ 8*(h&7))
  __shared__ ushort p_lds[4 * 16 * 64];

  const int tid  = threadIdx.x;
  const int wave = tid >> 6;
  const int lane = tid & 63;
  const int g    = lane >> 4;
  const int li   = lane & 15;
  const int b    = blockIdx.x >> 5;
  const int xw   = (blockIdx.x & 31) * 64 + wave * 16;

  // hoisted K A-frags (fp16): lane holds K[x=xw+li][h=kk*32+8g+e]
  f16x8 kf[4];
  {
    const float* kr = kp + ((size_t)(b * NS + xw + li)) * NH + g * 8;
    #pragma unroll
    for (int kk = 0; kk < 4; ++kk) {
      f32x4 a0 = *(const f32x4*)(kr + kk * 32);
      f32x4 a1 = *(const f32x4*)(kr + kk * 32 + 4);
      #pragma unroll
      for (int e = 0; e < 4; ++e) {
        kf[kk][e]     = (f16)a0[e];
        kf[kk][4 + e] = (f16)a1[e];
      }
    }
  }

  float m_[4], l_[4];
  f32x4 o_[8];
  #pragma unroll
  for (int r = 0; r < 4; ++r) { m_[r] = -INFINITY; l_[r] = 0.f; }
  #pragma unroll
  for (int h = 0; h < 8; ++h) o_[h] = (f32x4){0.f, 0.f, 0.f, 0.f};

  const float* qbp = qp + (size_t)b * NS * NH;
  const float* vbp = vp + (size_t)b * NS * NH;
  const ushort* qtile = PRECONV ? qws + (size_t)(b * YT_N) * 8192 : nullptr;
  const ushort* vtile = PRECONV ? vtws + (size_t)(b * YT_N) * 8192 : nullptr;

  auto stage = [&](int buf, int yt) {
    if constexpr (PRECONV) {
      const ushort* qs = qtile + (size_t)yt * 8192;
      const ushort* vs = vtile + (size_t)yt * 8192;
      int base = wave * 2048;                        // ushorts (4KB/wave)
      #pragma unroll
      for (int c = 0; c < 4; ++c) {
        gload_lds16(qs + base + c * 512 + lane * 8, &qb[buf][base + c * 512]);
        gload_lds16(vs + base + c * 512 + lane * 8, &vb[buf][base + c * 512]);
      }
    } else {
      const int yb = yt * 64;
      #pragma unroll
      for (int f = 0; f < 8; ++f) {
        int j = tid + 256 * f, rr = j >> 5, cc = (j & 31) << 2;
        f32x4 qv = *(const f32x4*)(qbp + (size_t)(yb + rr) * NH + cc);
        u16x4 hv;
        #pragma unroll
        for (int i = 0; i < 4; ++i) hv[i] = f2h(qv[i]);
        *(u16x4*)&qb[buf][rr * 128 + (cc ^ ((rr & 7) << 3))] = hv;
      }
      #pragma unroll
      for (int f = 0; f < 8; ++f) {
        int j = tid + 256 * f, rr = j >> 5, cc = (j & 31) << 2;
        f32x4 vv = *(const f32x4*)(vbp + (size_t)(yb + rr) * NH + cc);
        ushort mh[4];
        #pragma unroll
        for (int i = 0; i < 4; ++i) mh[i] = f2h(vv[i]);
        unsigned mx = (unsigned)mh[0] | ((unsigned)mh[1] << 16);
        unsigned my = (unsigned)mh[2] | ((unsigned)mh[3] << 16);
        unsigned ox = (unsigned)__shfl_xor((int)mx, 32);   // partner row rr^1
        unsigned oy = (unsigned)__shfl_xor((int)my, 16 + 16);
        oy = (unsigned)__shfl_xor((int)my, 32);
        ushort oh[4] = {(ushort)(ox & 0xffffu), (ushort)(ox >> 16),
                        (ushort)(oy & 0xffffu), (ushort)(oy >> 16)};
        int y2 = rr & ~1;
        int bi = (rr & 1) ? 2 : 0;
        #pragma unroll
        for (int i2 = 0; i2 < 2; ++i2) {
          int i = bi + i2;
          unsigned w = (rr & 1) ? ((unsigned)oh[i] | ((unsigned)mh[i] << 16))
                                : ((unsigned)mh[i] | ((unsigned)oh[i] << 16));
          int hcol = cc + i;
          *(unsigned*)&vb[buf][hcol * 64 + (y2 ^ ((hcol & 7) << 3))] = w;
        }
      }
    }
  };

  stage(0, 0);
  __syncthreads();
  int cur = 0;

  for (int yt = 0; yt < YT_N; ++yt) {
    if (yt + 1 < YT_N) stage(cur ^ 1, yt + 1);

    // ---- QK^T: fp16 single pass, 16 MFMA ----
    f32x4 sa[4];
    #pragma unroll
    for (int c = 0; c < 4; ++c) sa[c] = (f32x4){0.f, 0.f, 0.f, 0.f};
    #pragma unroll
    for (int c = 0; c < 4; ++c) {
      int y = 16 * c + li, rowoff = y * 128, sw = (y & 7) << 3;
      #pragma unroll
      for (int kk = 0; kk < 4; ++kk) {
        f16x8 qf = *(const f16x8*)&qb[cur][rowoff + ((kk * 32 + 8 * g) ^ sw)];
        sa[c] = __builtin_amdgcn_mfma_f32_16x16x32_f16(kf[kk], qf, sa[c], 0, 0, 0);
      }
    }

    // ---- online softmax over y; sa[c][r] = S[x=4g+r][y=16c+li] ----
    float rm[4];
    #pragma unroll
    for (int r = 0; r < 4; ++r)
      rm[r] = fmaxf(fmaxf(sa[0][r], sa[1][r]), fmaxf(sa[2][r], sa[3][r]));
    #pragma unroll
    for (int msk = 1; msk <= 8; msk <<= 1) {
      #pragma unroll
      for (int r = 0; r < 4; ++r) rm[r] = fmaxf(rm[r], __shfl_xor(rm[r], msk));
    }
    float mn[4], corr[4];
    #pragma unroll
    for (int r = 0; r < 4; ++r) {
      mn[r]   = fmaxf(m_[r], rm[r]);
      corr[r] = __expf(m_[r] - mn[r]);
      m_[r]   = mn[r];
    }
    float p[4][4];
    float rs[4] = {0.f, 0.f, 0.f, 0.f};
    #pragma unroll
    for (int c = 0; c < 4; ++c) {
      #pragma unroll
      for (int r = 0; r < 4; ++r) {
        float e = __expf(sa[c][r] - mn[r]);
        p[c][r] = e;
        rs[r] += e;
      }
    }
    #pragma unroll
    for (int msk = 1; msk <= 8; msk <<= 1) {
      #pragma unroll
      for (int r = 0; r < 4; ++r) rs[r] += __shfl_xor(rs[r], msk);
    }
    #pragma unroll
    for (int r = 0; r < 4; ++r) l_[r] = l_[r] * corr[r] + rs[r];
    #pragma unroll
    for (int h = 0; h < 8; ++h) {
      #pragma unroll
      for (int r = 0; r < 4; ++r) o_[h][r] *= corr[r];
    }

    // ---- P -> per-wave LDS (fp16, swizzled) ----
    ushort* pw = p_lds + wave * 1024;
    #pragma unroll
    for (int c = 0; c < 4; ++c) {
      #pragma unroll
      for (int r = 0; r < 4; ++r) {
        int row = 4 * g + r;
        pw[row * 64 + ((16 * c + li) ^ ((row & 7) << 3))] = f2h(p[c][r]);
      }
    }

    // ---- PV: O[16][128] += P[16][64] * V[64][128] ----
    const int swl = (li & 7) << 3;
    #pragma unroll
    for (int k2 = 0; k2 < 2; ++k2) {
      f16x8 pa = *(const f16x8*)&pw[li * 64 + ((k2 * 32 + 8 * g) ^ swl)];
      #pragma unroll
      for (int hs = 0; hs < 8; ++hs) {
        f16x8 vf = *(const f16x8*)&vb[cur][(hs * 16 + li) * 64 + ((k2 * 32 + 8 * g) ^ swl)];
        o_[hs] = __builtin_amdgcn_mfma_f32_16x16x32_f16(pa, vf, o_[hs], 0, 0, 0);
      }
    }
    __syncthreads();
    cur ^= 1;
  }

  // ---- epilogue ----
  float inv[4];
  #pragma unroll
  for (int r = 0; r < 4; ++r) inv[r] = 1.0f / l_[r];
  float* ob = op + ((size_t)(b * NS + xw)) * NH;
  #pragma unroll
  for (int hs = 0; hs < 8; ++hs) {
    #pragma unroll
    for (int r = 0; r < 4; ++r)
      ob[(size_t)(4 * g + r) * NH + hs * 16 + li] = o_[hs][r] * inv[r];
  }
}

extern "C" void kernel_launch(void* const* d_in, const int* in_sizes, int n_in,
                              void* d_out, int out_size, void* d_ws, size_t ws_size,
                              hipStream_t stream) {
  const float* q = (const float*)d_in[0];
  const float* k = (const float*)d_in[1];
  const float* v = (const float*)d_in[2];
  float* out = (float*)d_out;

  const size_t elems = (size_t)NB * NS * NH;          // 4.19M
  const size_t need  = elems * 2 * sizeof(ushort);    // Q + V^T fp16 = 16.78 MB

  if (d_ws && ws_size >= need) {
    ushort* qws  = (ushort*)d_ws;
    ushort* vtws = qws + elems;
    hipLaunchKernelGGL(conv_q_kernel, dim3(2048), dim3(256), 0, stream, q, qws);
    hipLaunchKernelGGL(conv_vt_kernel, dim3(512), dim3(256), 0, stream, v, vtws);
    hipLaunchKernelGGL((attn_main<true>), dim3(NB * YT_N), dim3(256), 0, stream,
                       q, k, v, out, qws, vtws);
  } else {
    hipLaunchKernelGGL((attn_main<false>), dim3(NB * YT_N), dim3(256), 0, stream,
                       q, k, v, out, (const ushort*)nullptr, (const ushort*)nullptr);
  }
}